// Round 4
// baseline (799.086 us; speedup 1.0000x reference)
//
#include <hip/hip_runtime.h>

// x (B,I); w/s/t (O,I); out (B,O), all fp32.
#define B_SZ 256
#define O_SZ 1024
#define I_SZ 1024

#define TB  8      // b-values per lane (accumulated in regs)
#define MO  2      // o-values per lane (x-load reuse)
#define SLN 32     // lanes splitting i (per half-wave)
#define KITERS (I_SZ / (SLN * 4))   // 8: 128 floats of i per iter

// out[b,o] = sum_i w[o,i] * phi((x[b,i]-t[o,i])/s[o,i]),  phi(z) = -z*exp(-0.5 z^2)
// Reformulated: u = z*K (K=sqrt(0.5*log2 e)) -> exp2(-u^2) = exp(-z^2/2)
//               y = w*z ; contribution = -y * exp2(-u^2)
// u = fma(x, rs*K, -t*rs*K), y = fma(x, w*rs, -t*w*rs): 4 VALU + 1 exp per element.
__launch_bounds__(256, 3)
__global__ void wavkan_dog_kernel(const float* __restrict__ X,
                                  const float* __restrict__ W,
                                  const float* __restrict__ S,
                                  const float* __restrict__ T,
                                  float* __restrict__ Out) {
    const int tid  = threadIdx.x;
    const int wave = tid >> 6;        // 0..3
    const int lane = tid & 63;
    const int half = lane >> 5;       // 0..1 : which o-pair within the wave
    const int sl   = lane & (SLN - 1);// 0..31: i-split lane

    const int o0 = blockIdx.x * 16 + wave * 4 + half * MO;  // 16 o's per block
    const int b0 = blockIdx.y * TB;

    const float K = 0.84932180028801904272f; // sqrt(0.5 * log2(e))

    float acc[MO][TB];
#pragma unroll
    for (int oo = 0; oo < MO; ++oo)
#pragma unroll
        for (int j = 0; j < TB; ++j) acc[oo][j] = 0.0f;

    const size_t r0 = (size_t)o0 * I_SZ + (size_t)(sl * 4);
    const float* w0 = W + r0;           const float* w1 = w0 + I_SZ;
    const float* s0 = S + r0;           const float* s1 = s0 + I_SZ;
    const float* t0 = T + r0;           const float* t1 = t0 + I_SZ;
    const float* xc = X + (size_t)b0 * I_SZ + (size_t)(sl * 4);

#pragma unroll
    for (int k = 0; k < KITERS; ++k) {
        const int i = k * (SLN * 4);   // byte offset k*512 -> 13-bit imm after unroll

        const float4 w4[MO] = { *(const float4*)(w0 + i), *(const float4*)(w1 + i) };
        const float4 s4[MO] = { *(const float4*)(s0 + i), *(const float4*)(s1 + i) };
        const float4 t4[MO] = { *(const float4*)(t0 + i), *(const float4*)(t1 + i) };
        float4 xv[TB];
#pragma unroll
        for (int j = 0; j < TB; ++j)
            xv[j] = *(const float4*)(xc + (size_t)j * I_SZ + i);

        // per-(o,c) coefficients, amortized over TB elements
        float rsk[MO][4], trsk[MO][4], wrs[MO][4], wtrs[MO][4];
#pragma unroll
        for (int oo = 0; oo < MO; ++oo) {
            const float sa[4] = {s4[oo].x, s4[oo].y, s4[oo].z, s4[oo].w};
            const float ta[4] = {t4[oo].x, t4[oo].y, t4[oo].z, t4[oo].w};
            const float wa[4] = {w4[oo].x, w4[oo].y, w4[oo].z, w4[oo].w};
#pragma unroll
            for (int c = 0; c < 4; ++c) {
                const float rs = __builtin_amdgcn_rcpf(sa[c]);
                rsk[oo][c]  = rs * K;
                trsk[oo][c] = ta[c] * rsk[oo][c];
                wrs[oo][c]  = wa[c] * rs;
                wtrs[oo][c] = ta[c] * wrs[oo][c];
            }
        }

#pragma unroll
        for (int c = 0; c < 4; ++c) {
            const float xs[TB] = { ((const float*)&xv[0])[c], ((const float*)&xv[1])[c],
                                   ((const float*)&xv[2])[c], ((const float*)&xv[3])[c],
                                   ((const float*)&xv[4])[c], ((const float*)&xv[5])[c],
                                   ((const float*)&xv[6])[c], ((const float*)&xv[7])[c] };
#pragma unroll
            for (int oo = 0; oo < MO; ++oo) {
                const float rk = rsk[oo][c], tk = trsk[oo][c];
                const float wr = wrs[oo][c], wt = wtrs[oo][c];
#pragma unroll
                for (int j = 0; j < TB; ++j) {
                    const float u = fmaf(xs[j], rk, -tk);        // z*K
                    const float m = u * (-u);                    // -z^2*K^2
                    const float e = __builtin_amdgcn_exp2f(m);   // exp(-z^2/2)
                    const float y = fmaf(xs[j], wr, -wt);        // w*z
                    acc[oo][j] = fmaf(-y, e, acc[oo][j]);        // += -w*z*e
                }
            }
        }
    }

    // Reduce across the 32 i-split lanes (xor 1..16 stays within the half)
#pragma unroll
    for (int m = 1; m < SLN; m <<= 1)
#pragma unroll
        for (int oo = 0; oo < MO; ++oo)
#pragma unroll
            for (int j = 0; j < TB; ++j)
                acc[oo][j] += __shfl_xor(acc[oo][j], m, 64);

    // Lanes sl<TB write out[b0+sl, o0..o0+1] (contiguous pair -> float2)
    if (sl < TB) {
        float v0 = 0.0f, v1 = 0.0f;
#pragma unroll
        for (int j = 0; j < TB; ++j)
            if (sl == j) { v0 = acc[0][j]; v1 = acc[1][j]; }
        *(float2*)(Out + (size_t)(b0 + sl) * O_SZ + o0) = make_float2(v0, v1);
    }
}

extern "C" void kernel_launch(void* const* d_in, const int* in_sizes, int n_in,
                              void* d_out, int out_size, void* d_ws, size_t ws_size,
                              hipStream_t stream) {
    const float* x = (const float*)d_in[0];   // (B, I)
    const float* w = (const float*)d_in[1];   // (O, I)
    const float* s = (const float*)d_in[2];   // (O, I)
    const float* t = (const float*)d_in[3];   // (O, I)
    float* out = (float*)d_out;               // (B, O)

    dim3 grid(O_SZ / 16, B_SZ / TB);          // (64, 32) = 2048 blocks
    wavkan_dog_kernel<<<grid, 256, 0, stream>>>(x, w, s, t, out);
}

// Round 5
// 534.925 us; speedup vs baseline: 1.4938x; 1.4938x over previous
//
#include <hip/hip_runtime.h>

// x (B,I); w/s/t (O,I); out (B,O), all fp32.
#define B_SZ 256
#define O_SZ 1024
#define I_SZ 1024

#define TB  8      // b-values per lane (accumulated in regs)
#define MO  2      // o-values per lane (x-load reuse)
#define SLN 32     // lanes splitting i (per half-wave)
#define KITERS (I_SZ / (SLN * 4))   // 8: 128 floats of i per iter

// out[b,o] = sum_i w[o,i] * phi((x[b,i]-t[o,i])/s[o,i]),  phi(z) = -z*exp(-0.5 z^2)
// Reformulated (4 VALU + 1 exp per element):
//   u = z*K (K=sqrt(0.5*log2 e)) -> exp2(-u^2) = exp(-z^2/2)
//   y = w*z ; contribution = -y * exp2(-u^2)
//   u = fma(x, rs*K, -(t*rs*K)), y = fma(x, w*rs, -(t*w*rs))
//
// NOTE (round-4 post-mortem): full k-unroll spills to scratch (WRITE_SIZE 1.3 GB,
// 12x regression). Keep the rolled/unroll-2 loop and small arrays (60-84 VGPR regime).
// launch_bounds(256,6): cap VGPR at 84, allow 6 waves/SIMD (round 3's (256,4) left 35% idle).
__launch_bounds__(256, 6)
__global__ void wavkan_dog_kernel(const float* __restrict__ X,
                                  const float* __restrict__ W,
                                  const float* __restrict__ S,
                                  const float* __restrict__ T,
                                  float* __restrict__ Out) {
    const int tid  = threadIdx.x;
    const int wave = tid >> 6;        // 0..3
    const int lane = tid & 63;
    const int half = lane >> 5;       // 0..1 : which o-pair within the wave
    const int sl   = lane & (SLN - 1);// 0..31: i-split lane

    const int o0 = blockIdx.x * 16 + wave * 4 + half * MO;  // 16 o's per block
    const int b0 = blockIdx.y * TB;

    const float K = 0.84932180028801904272f; // sqrt(0.5 * log2(e))

    float acc[MO][TB];
#pragma unroll
    for (int oo = 0; oo < MO; ++oo)
#pragma unroll
        for (int j = 0; j < TB; ++j) acc[oo][j] = 0.0f;

    const size_t r0 = (size_t)o0 * I_SZ + (size_t)(sl * 4);
    const float* w0 = W + r0;           const float* w1 = w0 + I_SZ;
    const float* s0 = S + r0;           const float* s1 = s0 + I_SZ;
    const float* t0 = T + r0;           const float* t1 = t0 + I_SZ;
    const float* xc = X + (size_t)b0 * I_SZ + (size_t)(sl * 4);

#pragma unroll 2
    for (int k = 0; k < KITERS; ++k) {
        const int i = k * (SLN * 4);

        const float4 w4[MO] = { *(const float4*)(w0 + i), *(const float4*)(w1 + i) };
        const float4 s4[MO] = { *(const float4*)(s0 + i), *(const float4*)(s1 + i) };
        const float4 t4[MO] = { *(const float4*)(t0 + i), *(const float4*)(t1 + i) };
        float4 xv[TB];
#pragma unroll
        for (int j = 0; j < TB; ++j)
            xv[j] = *(const float4*)(xc + (size_t)j * I_SZ + i);

        // per-(o,c) coefficients, amortized over TB=8 elements each
        float rsk[MO][4], trsk[MO][4], wrs[MO][4], wtrs[MO][4];
#pragma unroll
        for (int oo = 0; oo < MO; ++oo) {
            const float sa[4] = {s4[oo].x, s4[oo].y, s4[oo].z, s4[oo].w};
            const float ta[4] = {t4[oo].x, t4[oo].y, t4[oo].z, t4[oo].w};
            const float wa[4] = {w4[oo].x, w4[oo].y, w4[oo].z, w4[oo].w};
#pragma unroll
            for (int c = 0; c < 4; ++c) {
                const float rs = __builtin_amdgcn_rcpf(sa[c]);
                rsk[oo][c]  = rs * K;
                trsk[oo][c] = ta[c] * rsk[oo][c];
                wrs[oo][c]  = wa[c] * rs;
                wtrs[oo][c] = ta[c] * wrs[oo][c];
            }
        }

#pragma unroll
        for (int c = 0; c < 4; ++c) {
            const float xs[TB] = { ((const float*)&xv[0])[c], ((const float*)&xv[1])[c],
                                   ((const float*)&xv[2])[c], ((const float*)&xv[3])[c],
                                   ((const float*)&xv[4])[c], ((const float*)&xv[5])[c],
                                   ((const float*)&xv[6])[c], ((const float*)&xv[7])[c] };
#pragma unroll
            for (int oo = 0; oo < MO; ++oo) {
                const float rk = rsk[oo][c], tk = trsk[oo][c];
                const float wr = wrs[oo][c], wt = wtrs[oo][c];
#pragma unroll
                for (int j = 0; j < TB; ++j) {
                    const float u = fmaf(xs[j], rk, -tk);        // z*K
                    const float m = u * (-u);                    // -(z*K)^2
                    const float e = __builtin_amdgcn_exp2f(m);   // exp(-z^2/2)
                    const float y = fmaf(xs[j], wr, -wt);        // w*z
                    acc[oo][j] = fmaf(-y, e, acc[oo][j]);        // += -w*z*e
                }
            }
        }
    }

    // Reduce across the 32 i-split lanes (xor 1..16 stays within the half)
#pragma unroll
    for (int m = 1; m < SLN; m <<= 1)
#pragma unroll
        for (int oo = 0; oo < MO; ++oo)
#pragma unroll
            for (int j = 0; j < TB; ++j)
                acc[oo][j] += __shfl_xor(acc[oo][j], m, 64);

    // Lanes sl<TB write out[b0+sl, o0..o0+1] (contiguous pair -> float2)
    if (sl < TB) {
        float v0 = 0.0f, v1 = 0.0f;
#pragma unroll
        for (int j = 0; j < TB; ++j)
            if (sl == j) { v0 = acc[0][j]; v1 = acc[1][j]; }
        *(float2*)(Out + (size_t)(b0 + sl) * O_SZ + o0) = make_float2(v0, v1);
    }
}

extern "C" void kernel_launch(void* const* d_in, const int* in_sizes, int n_in,
                              void* d_out, int out_size, void* d_ws, size_t ws_size,
                              hipStream_t stream) {
    const float* x = (const float*)d_in[0];   // (B, I)
    const float* w = (const float*)d_in[1];   // (O, I)
    const float* s = (const float*)d_in[2];   // (O, I)
    const float* t = (const float*)d_in[3];   // (O, I)
    float* out = (float*)d_out;               // (B, O)

    dim3 grid(O_SZ / 16, B_SZ / TB);          // (64, 32) = 2048 blocks
    wavkan_dog_kernel<<<grid, 256, 0, stream>>>(x, w, s, t, out);
}

// Round 6
// 128.525 us; speedup vs baseline: 6.2174x; 4.1620x over previous
//
#include <hip/hip_runtime.h>

// x (B,I); w/s/t (O,I); out (B,O), all fp32.
#define B_SZ 256
#define O_SZ 1024
#define I_SZ 1024

#define TB  8      // b-values per lane (accumulated in regs)
#define MO  2      // o-values per lane (x-load reuse)
#define SLN 32     // lanes splitting i (per half-wave)
#define KITERS (I_SZ / (SLN * 4))   // 8: 128 floats of i per iter

typedef float v2f __attribute__((ext_vector_type(2)));

// out[b,o] = sum_i w[o,i] * phi((x[b,i]-t[o,i])/s[o,i]),  phi(z) = -z*exp(-0.5 z^2)
// Reformulated (4 fma-class + 1 exp per element):
//   u = fma(x, rs*K, -(t*rs*K))  (= z*K, K = sqrt(0.5*log2 e))
//   y = fma(x, w*rs, -(t*w*rs))  (= w*z)
//   acc = fma(-y, exp2(-u*u), acc)
// fma/mul chains are packed over float4 component PAIRS (adjacent VGPRs from the
// vector loads) -> v_pk_fma_f32 / v_pk_mul_f32 (CDNA full-rate packed fp32),
// halving VALU issue. exp2 stays scalar on the trans pipe.
//
// Register-pressure history: full unroll -> scratch spill (R4, 12x regress);
// launch_bounds(256,6) cap -> scratch spill (R5, 8x regress). (256,4) + rolled
// loop is the stable regime; unroll pinned to 1 because the packed version's
// live set (~110 VGPR) leaves no room for a 2x unroll under the 128 cap.
__launch_bounds__(256, 4)
__global__ void wavkan_dog_kernel(const float* __restrict__ X,
                                  const float* __restrict__ W,
                                  const float* __restrict__ S,
                                  const float* __restrict__ T,
                                  float* __restrict__ Out) {
    const int tid  = threadIdx.x;
    const int wave = tid >> 6;        // 0..3
    const int lane = tid & 63;
    const int half = lane >> 5;       // 0..1 : which o-pair within the wave
    const int sl   = lane & (SLN - 1);// 0..31: i-split lane

    const int o0 = blockIdx.x * 16 + wave * 4 + half * MO;  // 16 o's per block
    const int b0 = blockIdx.y * TB;

    const float K = 0.84932180028801904272f; // sqrt(0.5 * log2(e))

    v2f acc2[MO][TB];
#pragma unroll
    for (int oo = 0; oo < MO; ++oo)
#pragma unroll
        for (int j = 0; j < TB; ++j) acc2[oo][j] = (v2f)(0.0f);

    const size_t r0 = (size_t)o0 * I_SZ + (size_t)(sl * 4);
    const float* w0 = W + r0;           const float* w1 = w0 + I_SZ;
    const float* s0 = S + r0;           const float* s1 = s0 + I_SZ;
    const float* t0 = T + r0;           const float* t1 = t0 + I_SZ;
    const float* xc = X + (size_t)b0 * I_SZ + (size_t)(sl * 4);

#pragma unroll 1
    for (int k = 0; k < KITERS; ++k) {
        const int i = k * (SLN * 4);

        const float4 w4[MO] = { *(const float4*)(w0 + i), *(const float4*)(w1 + i) };
        const float4 s4[MO] = { *(const float4*)(s0 + i), *(const float4*)(s1 + i) };
        const float4 t4[MO] = { *(const float4*)(t0 + i), *(const float4*)(t1 + i) };
        float4 xv[TB];
#pragma unroll
        for (int j = 0; j < TB; ++j)
            xv[j] = *(const float4*)(xc + (size_t)j * I_SZ + i);

        // per-(o, component-pair) packed coefficients, amortized over TB=8
        v2f rk2[MO][2], tk2n[MO][2], wr2[MO][2], wt2n[MO][2];
#pragma unroll
        for (int oo = 0; oo < MO; ++oo) {
            const float* sa = (const float*)&s4[oo];
            const float* ta = (const float*)&t4[oo];
            const float* wa = (const float*)&w4[oo];
#pragma unroll
            for (int cp = 0; cp < 2; ++cp) {
                const v2f r  = { __builtin_amdgcn_rcpf(sa[2*cp]),
                                 __builtin_amdgcn_rcpf(sa[2*cp+1]) };
                const v2f tt = { ta[2*cp], ta[2*cp+1] };
                const v2f ww = { wa[2*cp], wa[2*cp+1] };
                rk2[oo][cp]  = r * K;
                tk2n[oo][cp] = -(tt * rk2[oo][cp]);
                wr2[oo][cp]  = ww * r;
                wt2n[oo][cp] = -(tt * wr2[oo][cp]);
            }
        }

#pragma unroll
        for (int cp = 0; cp < 2; ++cp) {
#pragma unroll
            for (int j = 0; j < TB; ++j) {
                const float* xp = (const float*)&xv[j];
                const v2f x2 = { xp[2*cp], xp[2*cp+1] };  // adjacent regs, no repack
#pragma unroll
                for (int oo = 0; oo < MO; ++oo) {
                    const v2f u = __builtin_elementwise_fma(x2, rk2[oo][cp], tk2n[oo][cp]);
                    const v2f m = -u * u;                        // -(z*K)^2
                    v2f e;
                    e.x = __builtin_amdgcn_exp2f(m.x);           // exp(-z^2/2)
                    e.y = __builtin_amdgcn_exp2f(m.y);
                    const v2f y = __builtin_elementwise_fma(x2, wr2[oo][cp], wt2n[oo][cp]);
                    acc2[oo][j] = __builtin_elementwise_fma(-y, e, acc2[oo][j]);
                }
            }
        }
    }

    // collapse component pairs, then reduce across the 32 i-split lanes
    float acc[MO][TB];
#pragma unroll
    for (int oo = 0; oo < MO; ++oo)
#pragma unroll
        for (int j = 0; j < TB; ++j)
            acc[oo][j] = acc2[oo][j].x + acc2[oo][j].y;

#pragma unroll
    for (int m = 1; m < SLN; m <<= 1)
#pragma unroll
        for (int oo = 0; oo < MO; ++oo)
#pragma unroll
            for (int j = 0; j < TB; ++j)
                acc[oo][j] += __shfl_xor(acc[oo][j], m, 64);

    // Lanes sl<TB write out[b0+sl, o0..o0+1] (contiguous pair -> float2)
    if (sl < TB) {
        float v0 = 0.0f, v1 = 0.0f;
#pragma unroll
        for (int j = 0; j < TB; ++j)
            if (sl == j) { v0 = acc[0][j]; v1 = acc[1][j]; }
        *(float2*)(Out + (size_t)(b0 + sl) * O_SZ + o0) = make_float2(v0, v1);
    }
}

extern "C" void kernel_launch(void* const* d_in, const int* in_sizes, int n_in,
                              void* d_out, int out_size, void* d_ws, size_t ws_size,
                              hipStream_t stream) {
    const float* x = (const float*)d_in[0];   // (B, I)
    const float* w = (const float*)d_in[1];   // (O, I)
    const float* s = (const float*)d_in[2];   // (O, I)
    const float* t = (const float*)d_in[3];   // (O, I)
    float* out = (float*)d_out;               // (B, O)

    dim3 grid(O_SZ / 16, B_SZ / TB);          // (64, 32) = 2048 blocks
    wavkan_dog_kernel<<<grid, 256, 0, stream>>>(x, w, s, t, out);
}

// Round 7
// 115.423 us; speedup vs baseline: 6.9231x; 1.1135x over previous
//
#include <hip/hip_runtime.h>

// x (B,I); w/s/t (O,I); out (B,O), all fp32.
#define B_SZ 256
#define O_SZ 1024
#define I_SZ 1024

#define TB  8      // b-values per lane (accumulated in regs)
#define MO  2      // o-values per lane (x-load reuse)
#define SLN 32     // lanes splitting i (per half-wave)
#define KITERS (I_SZ / (SLN * 4))   // 8: 128 floats of i per iter
#define ISTEP (SLN * 4)             // 128

typedef float v2f __attribute__((ext_vector_type(2)));

// out[b,o] = sum_i w[o,i] * phi((x[b,i]-t[o,i])/s[o,i]),  phi(z) = -z*exp(-0.5 z^2)
// u = K*(x-t)/s with K = sqrt(0.5*log2 e)  ->  exp2(-u^2) = exp(-z^2/2)
// w*z = u * (w/K)  ->  per (o,i): coeffs rk = K/s, tkn = -t*K/s, wk = w/K.
// Inner per 2 elements (packed over float4 component pairs -> v_pk_*_f32):
//   u = pk_fma(x, rk, tkn); m = pk_mul(u, -u); e = 2x v_exp_f32;
//   y = pk_mul(u, wk);      acc = pk_fma(-y, e, acc)        = 4 pk + 2 exp.
// Busy floor is the trans pipe (~12-16 cyc per wave v_exp_f32).
//
// Round-6 post-mortem: unroll-1 rolled loop exposed full load latency each iter
// (idle 56%). This version explicitly double-buffers ALL loads one iteration
// ahead: coeffs(cur) -> issue loads(nxt) -> elem compute(cur). Peak live set
// ~145 VGPR -> (256,3) cap 168. History: full unroll spilled (R4), (256,6)
// cap spilled (R5) -- watch WRITE_SIZE ~1 MB as the no-spill signal.
struct WST { float4 w[MO], s[MO], t[MO]; };
struct Coef { v2f rk[MO][2], tkn[MO][2], wk[MO][2]; };

__device__ __forceinline__ void load_wst(WST& b,
    const float* w0, const float* w1, const float* s0, const float* s1,
    const float* t0, const float* t1, int i) {
    b.w[0] = *(const float4*)(w0 + i);  b.w[1] = *(const float4*)(w1 + i);
    b.s[0] = *(const float4*)(s0 + i);  b.s[1] = *(const float4*)(s1 + i);
    b.t[0] = *(const float4*)(t0 + i);  b.t[1] = *(const float4*)(t1 + i);
}

__device__ __forceinline__ void load_x(float4 (&x)[TB], const float* xc, int i) {
#pragma unroll
    for (int j = 0; j < TB; ++j)
        x[j] = *(const float4*)(xc + (size_t)j * I_SZ + i);
}

__device__ __forceinline__ void make_coef(const WST& b, Coef& c) {
    const float K  = 0.84932180028801904272f;  // sqrt(0.5 * log2 e)
    const float iK = 1.17741002251547469101f;  // 1/K
#pragma unroll
    for (int oo = 0; oo < MO; ++oo) {
        const float* sa = (const float*)&b.s[oo];
        const float* ta = (const float*)&b.t[oo];
        const float* wa = (const float*)&b.w[oo];
#pragma unroll
        for (int cp = 0; cp < 2; ++cp) {
            const v2f r  = { __builtin_amdgcn_rcpf(sa[2*cp]),
                             __builtin_amdgcn_rcpf(sa[2*cp+1]) };
            const v2f tt = { ta[2*cp], ta[2*cp+1] };
            const v2f ww = { wa[2*cp], wa[2*cp+1] };
            c.rk[oo][cp]  = r * K;
            c.tkn[oo][cp] = -(tt * c.rk[oo][cp]);
            c.wk[oo][cp]  = ww * iK;
        }
    }
}

__device__ __forceinline__ void accum(const float4 (&xv)[TB], const Coef& c,
                                      v2f (&acc)[MO][TB]) {
#pragma unroll
    for (int cp = 0; cp < 2; ++cp) {
#pragma unroll
        for (int j = 0; j < TB; ++j) {
            const float* xp = (const float*)&xv[j];
            const v2f x2 = { xp[2*cp], xp[2*cp+1] };   // adjacent regs, no repack
#pragma unroll
            for (int oo = 0; oo < MO; ++oo) {
                const v2f u = __builtin_elementwise_fma(x2, c.rk[oo][cp], c.tkn[oo][cp]);
                const v2f m = u * (-u);                  // -(z*K)^2, neg modifier
                v2f e;
                e.x = __builtin_amdgcn_exp2f(m.x);       // exp(-z^2/2)
                e.y = __builtin_amdgcn_exp2f(m.y);
                const v2f y = u * c.wk[oo][cp];          // w*z
                acc[oo][j] = __builtin_elementwise_fma(-y, e, acc[oo][j]);
            }
        }
    }
}

__launch_bounds__(256, 3)
__global__ void wavkan_dog_kernel(const float* __restrict__ X,
                                  const float* __restrict__ W,
                                  const float* __restrict__ S,
                                  const float* __restrict__ T,
                                  float* __restrict__ Out) {
    const int tid  = threadIdx.x;
    const int wave = tid >> 6;
    const int lane = tid & 63;
    const int half = lane >> 5;
    const int sl   = lane & (SLN - 1);

    const int o0 = blockIdx.x * 16 + wave * 4 + half * MO;  // 16 o's per block
    const int b0 = blockIdx.y * TB;

    v2f acc[MO][TB];
#pragma unroll
    for (int oo = 0; oo < MO; ++oo)
#pragma unroll
        for (int j = 0; j < TB; ++j) acc[oo][j] = (v2f)(0.0f);

    const size_t r0 = (size_t)o0 * I_SZ + (size_t)(sl * 4);
    const float* w0 = W + r0;           const float* w1 = w0 + I_SZ;
    const float* s0 = S + r0;           const float* s1 = s0 + I_SZ;
    const float* t0 = T + r0;           const float* t1 = t0 + I_SZ;
    const float* xc = X + (size_t)b0 * I_SZ + (size_t)(sl * 4);

    WST wstA, wstB;
    float4 xA[TB], xB[TB];
    Coef C;

    load_wst(wstA, w0, w1, s0, s1, t0, t1, 0);
    load_x(xA, xc, 0);

#pragma unroll 1
    for (int k = 0; k < KITERS; k += 2) {
        // phase A: coeffs from A (frees A's w/s/t), prefetch k+1 into B, compute A
        const int i1 = ((k + 1) & (KITERS - 1)) * ISTEP;
        make_coef(wstA, C);
        load_wst(wstB, w0, w1, s0, s1, t0, t1, i1);
        load_x(xB, xc, i1);
        accum(xA, C, acc);

        // phase B: coeffs from B, prefetch k+2 into A (wraps to 0 on last — harmless), compute B
        const int i2 = ((k + 2) & (KITERS - 1)) * ISTEP;
        make_coef(wstB, C);
        load_wst(wstA, w0, w1, s0, s1, t0, t1, i2);
        load_x(xA, xc, i2);
        accum(xB, C, acc);
    }

    // collapse component pairs, then reduce across the 32 i-split lanes
    float r[MO][TB];
#pragma unroll
    for (int oo = 0; oo < MO; ++oo)
#pragma unroll
        for (int j = 0; j < TB; ++j)
            r[oo][j] = acc[oo][j].x + acc[oo][j].y;

#pragma unroll
    for (int m = 1; m < SLN; m <<= 1)
#pragma unroll
        for (int oo = 0; oo < MO; ++oo)
#pragma unroll
            for (int j = 0; j < TB; ++j)
                r[oo][j] += __shfl_xor(r[oo][j], m, 64);

    if (sl < TB) {
        float v0 = 0.0f, v1 = 0.0f;
#pragma unroll
        for (int j = 0; j < TB; ++j)
            if (sl == j) { v0 = r[0][j]; v1 = r[1][j]; }
        *(float2*)(Out + (size_t)(b0 + sl) * O_SZ + o0) = make_float2(v0, v1);
    }
}

extern "C" void kernel_launch(void* const* d_in, const int* in_sizes, int n_in,
                              void* d_out, int out_size, void* d_ws, size_t ws_size,
                              hipStream_t stream) {
    const float* x = (const float*)d_in[0];   // (B, I)
    const float* w = (const float*)d_in[1];   // (O, I)
    const float* s = (const float*)d_in[2];   // (O, I)
    const float* t = (const float*)d_in[3];   // (O, I)
    float* out = (float*)d_out;               // (B, O)

    dim3 grid(O_SZ / 16, B_SZ / TB);          // (64, 32) = 2048 blocks
    wavkan_dog_kernel<<<grid, 256, 0, stream>>>(x, w, s, t, out);
}

// Round 8
// 114.225 us; speedup vs baseline: 6.9957x; 1.0105x over previous
//
#include <hip/hip_runtime.h>

// x (B,I); w/s/t (O,I); out (B,O), all fp32.
#define B_SZ 256
#define O_SZ 1024
#define I_SZ 1024

#define TB  8      // b-values per block (x tile rows in LDS)
#define MO  2      // o-values per lane
#define SLN 32     // lanes splitting i (per half-wave)
#define KITERS (I_SZ / (SLN * 4))   // 8: 128 floats of i per iter
#define ISTEP (SLN * 4)             // 128

typedef float v2f __attribute__((ext_vector_type(2)));

// out[b,o] = sum_i w[o,i] * phi((x[b,i]-t[o,i])/s[o,i]),  phi(z) = -z*exp(-0.5 z^2)
// u = K*(x-t)/s, K = sqrt(0.5*log2 e)  ->  exp2(-u^2) = exp(-z^2/2);  w*z = u*(w/K).
// Packed over float4 component pairs -> v_pk_fma/mul_f32; exp2 scalar (trans pipe).
//
// Round-7 post-mortem: register double-buffering BOTH x and w/s/t made the live
// set ~140; the AMDGPU scheduler targeted 6 waves/SIMD (VGPR=84) on its own and
// SPILLED (WRITE_SIZE 12 MB). Fixes here:
//  1. x tile (32 KB, shared by all 4 waves, identical every iter) lives in LDS,
//     loaded once per block -> kills the 64-VGPR x buffers AND 4x redundant VMEM.
//  2. only w/s/t is register-double-buffered (24 VGPR/buffer).
//  3. amdgpu_waves_per_eu(4,4) PINS the scheduler's occupancy target (launch_bounds
//     min-waves alone is only a cap -- R7 proved the heuristic overrides it).
__attribute__((amdgpu_waves_per_eu(4, 4)))
__global__ void __launch_bounds__(256)
wavkan_dog_kernel(const float* __restrict__ X,
                  const float* __restrict__ W,
                  const float* __restrict__ S,
                  const float* __restrict__ T,
                  float* __restrict__ Out) {
    const int tid  = threadIdx.x;
    const int wave = tid >> 6;
    const int lane = tid & 63;
    const int half = lane >> 5;
    const int sl   = lane & (SLN - 1);

    const int o0 = blockIdx.x * 16 + wave * 4 + half * MO;  // 16 o's per block
    const int b0 = blockIdx.y * TB;

    __shared__ __align__(16) float xls[TB * I_SZ];          // 32 KB x tile

    // Prologue: flat cooperative copy of x[b0:b0+8][:] (contiguous 32 KB).
    {
        const float4* Xg4 = (const float4*)(X + (size_t)b0 * I_SZ);
        float4* L4 = (float4*)xls;
#pragma unroll
        for (int p = 0; p < (TB * I_SZ / 4) / 256; ++p)
            L4[tid + p * 256] = Xg4[tid + p * 256];
    }
    __syncthreads();

    v2f acc[MO][TB];
#pragma unroll
    for (int oo = 0; oo < MO; ++oo)
#pragma unroll
        for (int j = 0; j < TB; ++j) acc[oo][j] = (v2f)(0.0f);

    const size_t r0 = (size_t)o0 * I_SZ + (size_t)(sl * 4);
    const float* w0 = W + r0;           const float* w1 = w0 + I_SZ;
    const float* s0 = S + r0;           const float* s1 = s0 + I_SZ;
    const float* t0 = T + r0;           const float* t1 = t0 + I_SZ;
    const float* xb = xls + sl * 4;     // lane's column base in the LDS tile

    struct WST { float4 w[MO], s[MO], t[MO]; };
    struct Coef { v2f rk[MO][2], tkn[MO][2], wk[MO][2]; };

    auto load_wst = [&](WST& b, int i) {
        b.w[0] = *(const float4*)(w0 + i);  b.w[1] = *(const float4*)(w1 + i);
        b.s[0] = *(const float4*)(s0 + i);  b.s[1] = *(const float4*)(s1 + i);
        b.t[0] = *(const float4*)(t0 + i);  b.t[1] = *(const float4*)(t1 + i);
    };
    auto make_coef = [](const WST& b, Coef& c) {
        const float K  = 0.84932180028801904272f;  // sqrt(0.5 * log2 e)
        const float iK = 1.17741002251547469101f;  // 1/K
#pragma unroll
        for (int oo = 0; oo < MO; ++oo) {
            const float* sa = (const float*)&b.s[oo];
            const float* ta = (const float*)&b.t[oo];
            const float* wa = (const float*)&b.w[oo];
#pragma unroll
            for (int cp = 0; cp < 2; ++cp) {
                const v2f r  = { __builtin_amdgcn_rcpf(sa[2*cp]),
                                 __builtin_amdgcn_rcpf(sa[2*cp+1]) };
                const v2f tt = { ta[2*cp], ta[2*cp+1] };
                const v2f ww = { wa[2*cp], wa[2*cp+1] };
                c.rk[oo][cp]  = r * K;
                c.tkn[oo][cp] = -(tt * c.rk[oo][cp]);
                c.wk[oo][cp]  = ww * iK;
            }
        }
    };
    auto accum = [&](int i, const Coef& c) {
        float4 xv[TB];                                   // from LDS (ds_read_b128)
#pragma unroll
        for (int j = 0; j < TB; ++j)
            xv[j] = *(const float4*)(xb + j * I_SZ + i);
#pragma unroll
        for (int cp = 0; cp < 2; ++cp) {
#pragma unroll
            for (int j = 0; j < TB; ++j) {
                const float* xp = (const float*)&xv[j];
                const v2f x2 = { xp[2*cp], xp[2*cp+1] };
#pragma unroll
                for (int oo = 0; oo < MO; ++oo) {
                    const v2f u = __builtin_elementwise_fma(x2, c.rk[oo][cp], c.tkn[oo][cp]);
                    const v2f m = u * (-u);              // -(z*K)^2
                    v2f e;
                    e.x = __builtin_amdgcn_exp2f(m.x);   // exp(-z^2/2)
                    e.y = __builtin_amdgcn_exp2f(m.y);
                    const v2f y = u * c.wk[oo][cp];      // w*z
                    acc[oo][j] = __builtin_elementwise_fma(-y, e, acc[oo][j]);
                }
            }
        }
    };

    WST wstA, wstB;
    Coef C;
    load_wst(wstA, 0);

#pragma unroll 1
    for (int k = 0; k < KITERS; k += 2) {
        load_wst(wstB, ((k + 1) & (KITERS - 1)) * ISTEP);   // prefetch k+1
        make_coef(wstA, C);
        accum(k * ISTEP, C);

        load_wst(wstA, ((k + 2) & (KITERS - 1)) * ISTEP);   // prefetch k+2 (wraps; harmless)
        make_coef(wstB, C);
        accum((k + 1) * ISTEP, C);
    }

    // collapse component pairs, then reduce across the 32 i-split lanes
    float r[MO][TB];
#pragma unroll
    for (int oo = 0; oo < MO; ++oo)
#pragma unroll
        for (int j = 0; j < TB; ++j)
            r[oo][j] = acc[oo][j].x + acc[oo][j].y;

#pragma unroll
    for (int m = 1; m < SLN; m <<= 1)
#pragma unroll
        for (int oo = 0; oo < MO; ++oo)
#pragma unroll
            for (int j = 0; j < TB; ++j)
                r[oo][j] += __shfl_xor(r[oo][j], m, 64);

    if (sl < TB) {
        float v0 = 0.0f, v1 = 0.0f;
#pragma unroll
        for (int j = 0; j < TB; ++j)
            if (sl == j) { v0 = r[0][j]; v1 = r[1][j]; }
        *(float2*)(Out + (size_t)(b0 + sl) * O_SZ + o0) = make_float2(v0, v1);
    }
}

extern "C" void kernel_launch(void* const* d_in, const int* in_sizes, int n_in,
                              void* d_out, int out_size, void* d_ws, size_t ws_size,
                              hipStream_t stream) {
    const float* x = (const float*)d_in[0];   // (B, I)
    const float* w = (const float*)d_in[1];   // (O, I)
    const float* s = (const float*)d_in[2];   // (O, I)
    const float* t = (const float*)d_in[3];   // (O, I)
    float* out = (float*)d_out;               // (B, O)

    dim3 grid(O_SZ / 16, B_SZ / TB);          // (64, 32) = 2048 blocks
    wavkan_dog_kernel<<<grid, 256, 0, stream>>>(x, w, s, t, out);
}

// Round 9
// 112.532 us; speedup vs baseline: 7.1009x; 1.0150x over previous
//
#include <hip/hip_runtime.h>

// x (B,I); w/s/t (O,I); out (B,O), all fp32.
#define B_SZ 256
#define O_SZ 1024
#define I_SZ 1024

#define TB   8     // b rows per block (LDS x tile)
#define SLN  32    // lanes per half splitting i
#define KITERS (I_SZ / (SLN * 4))   // 8
#define ISTEP  (SLN * 4)            // 128

typedef float v2f __attribute__((ext_vector_type(2)));

// out[b,o] = sum_i w[o,i]*phi((x[b,i]-t[o,i])/s[o,i]),  phi(z) = -z*exp(-0.5 z^2)
// u = K*(x-t)/s, K = sqrt(0.5*log2 e) -> exp2(-u^2) = exp(-z^2/2);  w*z = u*(w/K)
// Packed over float4 component pairs -> v_pk_fma/mul_f32; exp2 scalar (trans pipe).
//
// R7/R8 lesson: the allocator targets 64-84 VGPR regardless of launch-bound caps
// and SPILLS live sets above it (WRITE_SIZE 12-16 MB). This round fits 64 by design:
//   - ONE o per lane-half (was 2): acc 16 + coef 12 + prefetch 12 + xv 4 + addr ~8 < 64
//   - x tile in LDS (32 KB/block, filled once; ds_read_b128 with pure-imm offsets)
//   - w/s/t prefetched one iter ahead in registers (12 regs only)
//   - latency otherwise hidden by TLP (LDS allows 5 blocks/CU)
__launch_bounds__(256, 4)
__global__ void wavkan_dog_kernel(const float* __restrict__ X,
                                  const float* __restrict__ W,
                                  const float* __restrict__ S,
                                  const float* __restrict__ T,
                                  float* __restrict__ Out) {
    const int tid  = threadIdx.x;
    const int wave = tid >> 6;
    const int lane = tid & 63;
    const int half = lane >> 5;
    const int sl   = lane & (SLN - 1);

    const int o  = blockIdx.x * 8 + wave * 2 + half;   // 8 o's per block
    const int b0 = blockIdx.y * TB;

    __shared__ __align__(16) float xls[TB * I_SZ];     // 32 KB

    {   // cooperative fill: x[b0:b0+8][:] is one contiguous 32 KB span
        const float4* Xg4 = (const float4*)(X + (size_t)b0 * I_SZ);
        float4* L4 = (float4*)xls;
#pragma unroll
        for (int p = 0; p < (TB * I_SZ / 4) / 256; ++p)
            L4[tid + p * 256] = Xg4[tid + p * 256];
    }
    __syncthreads();

    const float K  = 0.84932180028801904272f;  // sqrt(0.5 * log2 e)
    const float iK = 1.17741002251547469101f;  // 1/K

    v2f acc[TB];
#pragma unroll
    for (int j = 0; j < TB; ++j) acc[j] = (v2f)(0.0f);

    const int r0 = o * I_SZ + sl * 4;     // same 32-bit offset for W/S/T
    const float* wr = W + r0;
    const float* sr = S + r0;
    const float* tr = T + r0;
    const float* xb = xls + sl * 4;

    // one-iteration register prefetch of w/s/t (12 VGPRs)
    float4 sN = *(const float4*)(sr);
    float4 tN = *(const float4*)(tr);
    float4 wN = *(const float4*)(wr);

#pragma unroll 2
    for (int k = 0; k < KITERS; ++k) {
        const int i  = k * ISTEP;
        const int in = ((k + 1) & (KITERS - 1)) * ISTEP;   // wraps on last; harmless

        const float4 s4 = sN, t4 = tN, w4 = wN;
        sN = *(const float4*)(sr + in);                    // prefetch k+1
        tN = *(const float4*)(tr + in);
        wN = *(const float4*)(wr + in);

        v2f rk[2], tkn[2], wk[2];
        {
            const float* sa = (const float*)&s4;
            const float* ta = (const float*)&t4;
            const float* wa = (const float*)&w4;
#pragma unroll
            for (int cp = 0; cp < 2; ++cp) {
                const v2f r  = { __builtin_amdgcn_rcpf(sa[2*cp]),
                                 __builtin_amdgcn_rcpf(sa[2*cp+1]) };
                const v2f tt = { ta[2*cp], ta[2*cp+1] };
                const v2f ww = { wa[2*cp], wa[2*cp+1] };
                rk[cp]  = r * K;
                tkn[cp] = -(tt * rk[cp]);
                wk[cp]  = ww * iK;
            }
        }

#pragma unroll
        for (int j = 0; j < TB; ++j) {
            const float4 xv = *(const float4*)(xb + j * I_SZ + i);  // ds_read_b128, imm offset
            const float* xp = (const float*)&xv;
#pragma unroll
            for (int cp = 0; cp < 2; ++cp) {
                const v2f x2 = { xp[2*cp], xp[2*cp+1] };            // adjacent regs
                const v2f u  = __builtin_elementwise_fma(x2, rk[cp], tkn[cp]); // z*K
                const v2f m  = u * (-u);                            // -(z*K)^2
                v2f e;
                e.x = __builtin_amdgcn_exp2f(m.x);                  // exp(-z^2/2)
                e.y = __builtin_amdgcn_exp2f(m.y);
                const v2f y = u * wk[cp];                           // w*z
                acc[j] = __builtin_elementwise_fma(-y, e, acc[j]);  // += -w*z*e
            }
        }
    }

    // collapse component pairs, then reduce across the 32 i-split lanes
    float r[TB];
#pragma unroll
    for (int j = 0; j < TB; ++j) r[j] = acc[j].x + acc[j].y;

#pragma unroll
    for (int m = 1; m < SLN; m <<= 1)
#pragma unroll
        for (int j = 0; j < TB; ++j)
            r[j] += __shfl_xor(r[j], m, 64);

    // lanes sl<TB of each half write out[b0+sl, o]
    if (sl < TB) {
        float v = 0.0f;
#pragma unroll
        for (int j = 0; j < TB; ++j)
            if (sl == j) v = r[j];
        Out[(size_t)(b0 + sl) * O_SZ + o] = v;
    }
}

extern "C" void kernel_launch(void* const* d_in, const int* in_sizes, int n_in,
                              void* d_out, int out_size, void* d_ws, size_t ws_size,
                              hipStream_t stream) {
    const float* x = (const float*)d_in[0];   // (B, I)
    const float* w = (const float*)d_in[1];   // (O, I)
    const float* s = (const float*)d_in[2];   // (O, I)
    const float* t = (const float*)d_in[3];   // (O, I)
    float* out = (float*)d_out;               // (B, O)

    dim3 grid(O_SZ / 8, B_SZ / TB);           // (128, 32) = 4096 blocks
    wavkan_dog_kernel<<<grid, 256, 0, stream>>>(x, w, s, t, out);
}

// Round 10
// 110.184 us; speedup vs baseline: 7.2523x; 1.0213x over previous
//
#include <hip/hip_runtime.h>

// x (B,I); w/s/t (O,I); out (B,O), all fp32.
#define B_SZ 256
#define O_SZ 1024
#define I_SZ 1024

#define TB   8     // b rows per block (LDS x tile)
#define SLN  32    // lanes per half splitting i
#define KITERS (I_SZ / (SLN * 4))   // 8
#define ISTEP  (SLN * 4)            // 128
#define OITER  4                    // o-groups per block (32 o's/block)

typedef float v2f __attribute__((ext_vector_type(2)));

// out[b,o] = sum_i w[o,i]*phi((x[b,i]-t[o,i])/s[o,i]),  phi(z) = -z*exp(-0.5 z^2)
// u = K*(x-t)/s, K = sqrt(0.5*log2 e) -> exp2(-u^2) = exp(-z^2/2);  w*z = u*(w/K)
// Packed over float4 component pairs -> v_pk_fma/mul_f32; exp2 scalar (trans pipe).
//
// Measured model (R3/R6/R9 busy-cycle reconciliation): v_exp_f32 wave64 ~16 cyc ->
// trans pipe floor ~70k cyc/SIMD ~= 29 us. R9's remaining 37% idle = prologue/tail:
// 128 blocks re-filled the SAME x tile, 16 sequential block-rounds/CU.
// This round: each block loops over 4 o-groups reusing its tile; grid = 1024 blocks
// = exactly 4 resident/CU (128 KB LDS), no rounds, prologue amortized 4x.
// Register discipline (R4/R5/R7/R8 spills): inner body is R9's proven 44-VGPR
// structure; oi-loop pinned unroll 1.
__launch_bounds__(256, 4)
__global__ void wavkan_dog_kernel(const float* __restrict__ X,
                                  const float* __restrict__ W,
                                  const float* __restrict__ S,
                                  const float* __restrict__ T,
                                  float* __restrict__ Out) {
    const int tid  = threadIdx.x;
    const int wave = tid >> 6;
    const int lane = tid & 63;
    const int half = lane >> 5;
    const int sl   = lane & (SLN - 1);

    const int obase = blockIdx.x * (8 * OITER) + wave * 2 + half; // + oi*8
    const int b0    = blockIdx.y * TB;

    __shared__ __align__(16) float xls[TB * I_SZ];     // 32 KB

    const int r0 = obase * I_SZ + sl * 4;  // 32-bit offsets, same for W/S/T
    const float* wr = W + r0;
    const float* sr = S + r0;
    const float* tr = T + r0;

    // Issue first w/s/t prefetch BEFORE the LDS fill so it flies under the barrier.
    float4 sN = *(const float4*)(sr);
    float4 tN = *(const float4*)(tr);
    float4 wN = *(const float4*)(wr);

    {   // cooperative fill: x[b0:b0+8][:] is one contiguous 32 KB span
        const float4* Xg4 = (const float4*)(X + (size_t)b0 * I_SZ);
        float4* L4 = (float4*)xls;
#pragma unroll
        for (int p = 0; p < (TB * I_SZ / 4) / 256; ++p)
            L4[tid + p * 256] = Xg4[tid + p * 256];
    }
    __syncthreads();

    const float K  = 0.84932180028801904272f;  // sqrt(0.5 * log2 e)
    const float iK = 1.17741002251547469101f;  // 1/K
    const float* xb = xls + sl * 4;

#pragma unroll 1
    for (int oi = 0; oi < OITER; ++oi) {
        const int ob = oi * 8 * I_SZ;          // element offset to this o-group's rows

        v2f acc[TB];
#pragma unroll
        for (int j = 0; j < TB; ++j) acc[j] = (v2f)(0.0f);

#pragma unroll 2
        for (int k = 0; k < KITERS; ++k) {
            const int i = k * ISTEP;
            // prefetch k+1; at k==7 prefetch the NEXT o-group's k=0 (wraps to oi=0: L1-hot, harmless)
            const int in = (k < KITERS - 1) ? (ob + (k + 1) * ISTEP)
                                            : ((((oi + 1) & (OITER - 1)) * 8) * I_SZ);

            const float4 s4 = sN, t4 = tN, w4 = wN;
            sN = *(const float4*)(sr + in);
            tN = *(const float4*)(tr + in);
            wN = *(const float4*)(wr + in);

            v2f rk[2], tkn[2], wk[2];
            {
                const float* sa = (const float*)&s4;
                const float* ta = (const float*)&t4;
                const float* wa = (const float*)&w4;
#pragma unroll
                for (int cp = 0; cp < 2; ++cp) {
                    const v2f r  = { __builtin_amdgcn_rcpf(sa[2*cp]),
                                     __builtin_amdgcn_rcpf(sa[2*cp+1]) };
                    const v2f tt = { ta[2*cp], ta[2*cp+1] };
                    const v2f ww = { wa[2*cp], wa[2*cp+1] };
                    rk[cp]  = r * K;
                    tkn[cp] = -(tt * rk[cp]);
                    wk[cp]  = ww * iK;
                }
            }

#pragma unroll
            for (int j = 0; j < TB; ++j) {
                const float4 xv = *(const float4*)(xb + j * I_SZ + i); // ds_read_b128, imm offset
                const float* xp = (const float*)&xv;
#pragma unroll
                for (int cp = 0; cp < 2; ++cp) {
                    const v2f x2 = { xp[2*cp], xp[2*cp+1] };
                    const v2f u  = __builtin_elementwise_fma(x2, rk[cp], tkn[cp]); // z*K
                    const v2f m  = u * (-u);                                      // -(z*K)^2
                    v2f e;
                    e.x = __builtin_amdgcn_exp2f(m.x);                            // exp(-z^2/2)
                    e.y = __builtin_amdgcn_exp2f(m.y);
                    const v2f y = u * wk[cp];                                     // w*z
                    acc[j] = __builtin_elementwise_fma(-y, e, acc[j]);            // += -w*z*e
                }
            }
        }

        // collapse pairs, reduce across the 32 i-split lanes
        float r[TB];
#pragma unroll
        for (int j = 0; j < TB; ++j) r[j] = acc[j].x + acc[j].y;
#pragma unroll
        for (int m = 1; m < SLN; m <<= 1)
#pragma unroll
            for (int j = 0; j < TB; ++j)
                r[j] += __shfl_xor(r[j], m, 64);

        if (sl < TB) {
            float v = 0.0f;
#pragma unroll
            for (int j = 0; j < TB; ++j)
                if (sl == j) v = r[j];
            Out[(size_t)(b0 + sl) * O_SZ + (obase + oi * 8)] = v;
        }
    }
}

extern "C" void kernel_launch(void* const* d_in, const int* in_sizes, int n_in,
                              void* d_out, int out_size, void* d_ws, size_t ws_size,
                              hipStream_t stream) {
    const float* x = (const float*)d_in[0];   // (B, I)
    const float* w = (const float*)d_in[1];   // (O, I)
    const float* s = (const float*)d_in[2];   // (O, I)
    const float* t = (const float*)d_in[3];   // (O, I)
    float* out = (float*)d_out;               // (B, O)

    dim3 grid(O_SZ / (8 * OITER), B_SZ / TB); // (32, 32) = 1024 blocks = 4/CU resident
    wavkan_dog_kernel<<<grid, 256, 0, stream>>>(x, w, s, t, out);
}